// Round 2
// baseline (455.217 us; speedup 1.0000x reference)
//
#include <hip/hip_runtime.h>

#define DEVI __device__ __forceinline__

static constexpr float KEPS = 1e-8f;

DEVI float frcp(float x) { return __builtin_amdgcn_rcpf(x); }
DEVI float frsq(float x) { return __builtin_amdgcn_rsqf(x); }

struct F3 { float x, y, z; };  // 12B, align 4 -> global_load_dwordx3

// --- one symmetric Jacobi rotation on pair (p,q) ---
// app,aqq,apq: the 2x2 block; (b1p,b1q),(b2p,b2q): the two off-pair element
// pairs a[r][p],a[r][q]; v*p,v*q: columns p,q of the 4 eigenvector rows.
#define JR(app, aqq, apq, b1p, b1q, b2p, b2q, v0p, v0q, v1p, v1q, v2p, v2q, v3p, v3q) { \
  float th = 0.5f * (aqq - app) * frcp(apq);                                   \
  float sq = sqrtf(fmaf(th, th, 1.0f));                                        \
  float tt = frcp(th + copysignf(sq, th));                                     \
  tt = (fabsf(apq) > 1e-20f) ? tt : 0.0f;                                      \
  float cc = frsq(fmaf(tt, tt, 1.0f));                                         \
  float sn = tt * cc;                                                          \
  app = fmaf(-tt, apq, app); aqq = fmaf(tt, apq, aqq); apq = 0.0f;             \
  float u_;                                                                    \
  u_ = b1p; b1p = cc*u_ - sn*b1q; b1q = sn*u_ + cc*b1q;                        \
  u_ = b2p; b2p = cc*u_ - sn*b2q; b2q = sn*u_ + cc*b2q;                        \
  u_ = v0p; v0p = cc*u_ - sn*v0q; v0q = sn*u_ + cc*v0q;                        \
  u_ = v1p; v1p = cc*u_ - sn*v1q; v1q = sn*u_ + cc*v1q;                        \
  u_ = v2p; v2p = cc*u_ - sn*v2q; v2q = sn*u_ + cc*v2q;                        \
  u_ = v3p; v3p = cc*u_ - sn*v3q; v3q = sn*u_ + cc*v3q;                        \
}

// Apply rotation r about pivot p to child joint C.
template<int C>
DEVI void rotc(float tx[21], float ty[21], float tz[21],
               float px, float py, float pz,
               float r00, float r01, float r02,
               float r10, float r11, float r12,
               float r20, float r21, float r22) {
  float x = tx[C] - px, y = ty[C] - py, z = tz[C] - pz;
  tx[C] = r00*x + r01*y + r02*z + px;
  ty[C] = r10*x + r11*y + r12*z + py;
  tz[C] = r20*x + r21*y + r22*z + pz;
}

// Twist step: align bone PI->I toward centered target (gx,gy,gz).
// Direct child I updated via |v0|*v1_hat shortcut; C1/C2 (if NC>1/2) via full r.
template<int PI, int I, int NC, int C1, int C2>
DEVI void bone(float tx[21], float ty[21], float tz[21],
               float gx, float gy, float gz) {
  float px = tx[PI], py = ty[PI], pz = tz[PI];
  float v0x = tx[I] - px, v0y = ty[I] - py, v0z = tz[I] - pz;
  float v1x = gx - px,    v1y = gy - py,    v1z = gz - pz;
  float d0 = v0x*v0x + v0y*v0y + v0z*v0z;
  float d1 = v1x*v1x + v1y*v1y + v1z*v1z;
  float in0 = frcp(sqrtf(d0) + KEPS);
  float in1 = frcp(sqrtf(d1) + KEPS);
  // t[I] = p + |v0| * v1_hat   (== r @ v0 + p up to O(EPS))
  float sc = d0 * in0 * in1;
  float nix = fmaf(sc, v1x, px), niy = fmaf(sc, v1y, py), niz = fmaf(sc, v1z, pz);
  if constexpr (NC > 1) {
    float ax = v0x*in0, ay = v0y*in0, az = v0z*in0;
    float bx = v1x*in1, by = v1y*in1, bz = v1z*in1;
    float c = ax*bx + ay*by + az*bz;
    float cx = ay*bz - az*by, cy = az*bx - ax*bz, cz = ax*by - ay*bx;
    float s = sqrtf(cx*cx + cy*cy + cz*cz);
    float is = frcp(s + KEPS);
    float kx = cx*is, ky = cy*is, kz = cz*is;
    float omc = 1.0f - c;
    float r00 = 1.0f - omc*(ky*ky + kz*kz);
    float r11 = 1.0f - omc*(kx*kx + kz*kz);
    float r22 = 1.0f - omc*(kx*kx + ky*ky);
    float kxy = omc*kx*ky, kxz = omc*kx*kz, kyz = omc*ky*kz;
    float skx = s*kx, sky = s*ky, skz = s*kz;
    float r01 = kxy - skz, r10 = kxy + skz;
    float r02 = kxz + sky, r20 = kxz - sky;
    float r12 = kyz - skx, r21 = kyz + skx;
    rotc<C1>(tx, ty, tz, px, py, pz, r00, r01, r02, r10, r11, r12, r20, r21, r22);
    if constexpr (NC > 2)
      rotc<C2>(tx, ty, tz, px, py, pz, r00, r01, r02, r10, r11, r12, r20, r21, r22);
  }
  tx[I] = nix; ty[I] = niy; tz[I] = niz;
}

DEVI void st3(float* p, float x, float y, float z) {
  F3 v; v.x = x; v.y = y; v.z = z; *(F3*)p = v;
}

// Finger: base B, joints B+1, B+2, tip T. Reloads its 3 joint_gt targets,
// runs 3 bones, stores its 4 finalized output joints.
template<int B, int T>
DEVI void finger(const float* __restrict__ gp, float* __restrict__ op,
                 float wx, float wy, float wz,
                 float tx[21], float ty[21], float tz[21]) {
  F3 gA = *(const F3*)(gp + 3*(B+1));
  F3 gB = *(const F3*)(gp + 3*(B+2));
  F3 gC = *(const F3*)(gp + 3*T);
  bone<B,   B+1, 3, B+2, T>(tx, ty, tz, gA.x - wx, gA.y - wy, gA.z - wz);
  bone<B+1, B+2, 2, T,   T>(tx, ty, tz, gB.x - wx, gB.y - wy, gB.z - wz);
  bone<B+2, T,   1, T,   T>(tx, ty, tz, gC.x - wx, gC.y - wy, gC.z - wz);
  st3(op + 3*B,     tx[B]   + wx, ty[B]   + wy, tz[B]   + wz);
  st3(op + 3*(B+1), tx[B+1] + wx, ty[B+1] + wy, tz[B+1] + wz);
  st3(op + 3*(B+2), tx[B+2] + wx, ty[B+2] + wy, tz[B+2] + wz);
  st3(op + 3*T,     tx[T]   + wx, ty[T]   + wy, tz[T]   + wz);
}

__global__ void __launch_bounds__(64, 4)
kin_kernel(const float* __restrict__ joint_gt, const float* __restrict__ tempJ,
           float* __restrict__ out, int N) {
  int h = blockIdx.x * 64 + threadIdx.x;
  if (h >= N) return;
  const float* tp = tempJ    + (long long)h * 63;
  const float* gp = joint_gt + (long long)h * 63;
  float*       op = out      + (long long)h * 63;

  float tx[21], ty[21], tz[21];

  // ---- fused load pass: center tempJ -> t, accumulate H = t0^T @ (gt - w) ----
  F3 r0 = *(const F3*)tp;
  F3 w  = *(const F3*)gp;
  float H00 = 0, H01 = 0, H02 = 0, H10 = 0, H11 = 0, H12 = 0, H20 = 0, H21 = 0, H22 = 0;
  tx[0] = 0; ty[0] = 0; tz[0] = 0;
#pragma unroll
  for (int j = 1; j < 21; ++j) {
    F3 tv = *(const F3*)(tp + 3*j);
    F3 gv = *(const F3*)(gp + 3*j);
    float ax = tv.x - r0.x, ay = tv.y - r0.y, az = tv.z - r0.z;
    float bx = gv.x - w.x,  by = gv.y - w.y,  bz = gv.z - w.z;
    tx[j] = ax; ty[j] = ay; tz[j] = az;
    H00 = fmaf(ax, bx, H00); H01 = fmaf(ax, by, H01); H02 = fmaf(ax, bz, H02);
    H10 = fmaf(ay, bx, H10); H11 = fmaf(ay, by, H11); H12 = fmaf(ay, bz, H12);
    H20 = fmaf(az, bx, H20); H21 = fmaf(az, by, H21); H22 = fmaf(az, bz, H22);
  }

  // ---- Horn 4x4 N (10 unique elements), compact symmetric Jacobi, 5 sweeps ----
  float n00 =  H00 + H11 + H22;
  float n01 =  H12 - H21;
  float n02 =  H20 - H02;
  float n03 =  H01 - H10;
  float n11 =  H00 - H11 - H22;
  float n12 =  H01 + H10;
  float n13 =  H20 + H02;
  float n22 = -H00 + H11 - H22;
  float n23 =  H12 + H21;
  float n33 = -H00 - H11 + H22;
  float v00 = 1, v01 = 0, v02 = 0, v03 = 0;
  float v10 = 0, v11 = 1, v12 = 0, v13 = 0;
  float v20 = 0, v21 = 0, v22 = 1, v23 = 0;
  float v30 = 0, v31 = 0, v32 = 0, v33 = 1;
#pragma unroll
  for (int sw = 0; sw < 5; ++sw) {
    JR(n00, n11, n01, n02, n12, n03, n13, v00, v01, v10, v11, v20, v21, v30, v31);
    JR(n00, n22, n02, n01, n12, n03, n23, v00, v02, v10, v12, v20, v22, v30, v32);
    JR(n00, n33, n03, n01, n13, n02, n23, v00, v03, v10, v13, v20, v23, v30, v33);
    JR(n11, n22, n12, n01, n02, n13, n23, v01, v02, v11, v12, v21, v22, v31, v32);
    JR(n11, n33, n13, n01, n03, n12, n23, v01, v03, v11, v13, v21, v23, v31, v33);
    JR(n22, n33, n23, n02, n03, n12, n13, v02, v03, v12, v13, v22, v23, v32, v33);
  }
  // pick max-eigenvalue column
  float e = n00, qw = v00, qx = v10, qy = v20, qz = v30;
  { bool b = n11 > e; e = b ? n11 : e; qw = b ? v01 : qw; qx = b ? v11 : qx; qy = b ? v21 : qy; qz = b ? v31 : qz; }
  { bool b = n22 > e; e = b ? n22 : e; qw = b ? v02 : qw; qx = b ? v12 : qx; qy = b ? v22 : qy; qz = b ? v32 : qz; }
  { bool b = n33 > e; e = b ? n33 : e; qw = b ? v03 : qw; qx = b ? v13 : qx; qy = b ? v23 : qy; qz = b ? v33 : qz; }

  float R00 = 1.0f - 2.0f*(qy*qy + qz*qz), R01 = 2.0f*(qx*qy - qw*qz), R02 = 2.0f*(qx*qz + qw*qy);
  float R10 = 2.0f*(qx*qy + qw*qz), R11 = 1.0f - 2.0f*(qx*qx + qz*qz), R12 = 2.0f*(qy*qz - qw*qx);
  float R20 = 2.0f*(qx*qz - qw*qy), R21 = 2.0f*(qy*qz + qw*qx), R22 = 1.0f - 2.0f*(qx*qx + qy*qy);

  // ---- tJ = Rw @ t0 ----
#pragma unroll
  for (int j = 1; j < 21; ++j) {
    float x = tx[j], y = ty[j], z = tz[j];
    tx[j] = R00*x + R01*y + R02*z;
    ty[j] = R10*x + R11*y + R12*z;
    tz[j] = R20*x + R21*y + R22*z;
  }

  // ---- wrist output, then 5 independent finger chains (each stores its joints) ----
  st3(op, w.x, w.y, w.z);
  finger<1,  17>(gp, op, w.x, w.y, w.z, tx, ty, tz);
  finger<4,  18>(gp, op, w.x, w.y, w.z, tx, ty, tz);
  finger<7,  20>(gp, op, w.x, w.y, w.z, tx, ty, tz);
  finger<10, 19>(gp, op, w.x, w.y, w.z, tx, ty, tz);
  finger<13, 16>(gp, op, w.x, w.y, w.z, tx, ty, tz);
}

extern "C" void kernel_launch(void* const* d_in, const int* in_sizes, int n_in,
                              void* d_out, int out_size, void* d_ws, size_t ws_size,
                              hipStream_t stream) {
  const float* joint_gt = (const float*)d_in[0];
  const float* tempJ    = (const float*)d_in[1];
  float* out = (float*)d_out;
  int N = in_sizes[0] / 63;
  int blocks = (N + 63) / 64;
  hipLaunchKernelGGL(kin_kernel, dim3(blocks), dim3(64), 0, stream,
                     joint_gt, tempJ, out, N);
}